// Round 1
// baseline (458.034 us; speedup 1.0000x reference)
//
#include <hip/hip_runtime.h>

// Problem constants (B=2, S=8192, IN=2048, OUT=2048, L=4, R=32)
#define M_DIM 16384
#define N_DIM 2048
#define K_DIM 2048
#define L_AD 4
#define R_AD 32

typedef __bf16 bf16_t;
typedef bf16_t bf16x8 __attribute__((ext_vector_type(8)));
typedef bf16_t bf16x4 __attribute__((ext_vector_type(4)));
typedef float f32x4 __attribute__((ext_vector_type(4)));

#define BM 128
#define BN 128
#define BK 64
#define SA 72  // padded LDS stride for A tile (bf16 elems): conflict-free frag reads

__device__ __forceinline__ void async_load16(const void* g, void* l) {
  __builtin_amdgcn_global_load_lds(
      (const __attribute__((address_space(1))) unsigned int*)g,
      (__attribute__((address_space(3))) unsigned int*)l, 16, 0, 0);
}

// ---------------------------------------------------------------------------
// Kernel 1: Weff[n,k] = bf16( W[n,k] + sum_l scale_l * sum_r ups[l,n,r]*downs[l,r,k] )
// 64x64 tile per block, rank-128 inner loop, register-blocked 4x4.
// ---------------------------------------------------------------------------
__global__ __launch_bounds__(256) void build_weff_kernel(
    const float* __restrict__ W, const float* __restrict__ downs,
    const float* __restrict__ ups, const float* __restrict__ scales,
    bf16_t* __restrict__ weff) {
  __shared__ float up_s[64 * 129];   // [n_local][lr], stride 129 breaks bank aliasing
  __shared__ float down_s[128 * 64]; // [lr][k_local]
  const int t = threadIdx.x;
  const int n0 = blockIdx.y * 64;
  const int k0 = blockIdx.x * 64;

  for (int l = 0; l < L_AD; ++l) {
    const float sc = scales[l];
    const float* up_l = ups + (size_t)l * N_DIM * R_AD;
    #pragma unroll
    for (int j = 0; j < 8; ++j) {
      int flat = j * 256 + t;  // over 64*32
      int nl = flat >> 5, r = flat & 31;
      up_s[nl * 129 + l * 32 + r] = sc * up_l[(size_t)(n0 + nl) * R_AD + r];
    }
  }
  #pragma unroll
  for (int j = 0; j < 32; ++j) {
    int flat = j * 256 + t;  // over 128*64
    int lr = flat >> 6, kk = flat & 63;
    down_s[lr * 64 + kk] = downs[(size_t)lr * K_DIM + k0 + kk];
  }
  __syncthreads();

  const int tn = t >> 4, tk = t & 15;
  float acc[4][4] = {};
  for (int lr = 0; lr < L_AD * R_AD; ++lr) {
    f32x4 b = *(const f32x4*)&down_s[lr * 64 + tk * 4];
    #pragma unroll
    for (int u = 0; u < 4; ++u) {
      float a = up_s[(tn * 4 + u) * 129 + lr];
      #pragma unroll
      for (int v = 0; v < 4; ++v) acc[u][v] += a * b[v];
    }
  }
  #pragma unroll
  for (int u = 0; u < 4; ++u) {
    int n = n0 + tn * 4 + u;
    f32x4 wv = *(const f32x4*)&W[(size_t)n * K_DIM + k0 + tk * 4];
    bf16x4 o;
    #pragma unroll
    for (int v = 0; v < 4; ++v) o[v] = (bf16_t)(acc[u][v] + wv[v]);
    *(bf16x4*)&weff[(size_t)n * K_DIM + k0 + tk * 4] = o;
  }
}

// ---------------------------------------------------------------------------
// Kernel 2: out[m,n] = sum_k x[m,k]*Weff[n,k] + bias[n]
// 128x128 tile, BK=64, 4 waves (2x2), 4x4 16x16x32 bf16 MFMA per wave.
// A: fp32 global -> cvt bf16 -> padded LDS. B: global_load_lds 16B, XOR swizzle.
// ---------------------------------------------------------------------------
__global__ __launch_bounds__(256) void lora_gemm_kernel(
    const float* __restrict__ X, const bf16_t* __restrict__ Wb,
    const float* __restrict__ bias, float* __restrict__ out) {
  __shared__ __align__(16) bf16_t As[BM * SA];
  __shared__ __align__(16) bf16_t Bs[BN * BK];

  const int t = threadIdx.x;
  const int lane = t & 63;
  const int wv = t >> 6;
  const int wm = wv >> 1, wn = wv & 1;
  const int col = lane & 15, quad = lane >> 4;
  const int m0 = blockIdx.y * BM;
  const int n0 = blockIdx.x * BN;

  // staging decomposition: flat slot s = j*256 + t; row = s>>3 (8-elt octets)
  const int srow = t >> 3;  // 0..31
  const int soct = t & 7;   // 0..7

  f32x4 acc[4][4] = {};

  float bn[4];
  #pragma unroll
  for (int j = 0; j < 4; ++j) bn[j] = bias[n0 + wn * 64 + j * 16 + col];

  for (int kt = 0; kt < K_DIM / BK; ++kt) {
    const int kg = kt * BK;
    // B tile: 128 rows x 64 k (bf16). slot (n, p) holds chunk c = p ^ (n&7).
    #pragma unroll
    for (int j = 0; j < 4; ++j) {
      int n = j * 32 + srow;
      int c = soct ^ (n & 7);
      const bf16_t* src = Wb + (size_t)(n0 + n) * K_DIM + kg + c * 8;
      async_load16(src, &Bs[(size_t)(j * 256 + t) * 8]);
    }
    // A tile: 128 rows x 64 k, fp32 -> bf16, padded stride SA
    #pragma unroll
    for (int j = 0; j < 4; ++j) {
      int m = j * 32 + srow;
      const f32x4* src = (const f32x4*)(X + (size_t)(m0 + m) * K_DIM + kg + soct * 8);
      f32x4 lo = src[0], hi = src[1];
      bf16x8 v;
      v[0] = (bf16_t)lo[0]; v[1] = (bf16_t)lo[1];
      v[2] = (bf16_t)lo[2]; v[3] = (bf16_t)lo[3];
      v[4] = (bf16_t)hi[0]; v[5] = (bf16_t)hi[1];
      v[6] = (bf16_t)hi[2]; v[7] = (bf16_t)hi[3];
      *(bf16x8*)&As[m * SA + soct * 8] = v;
    }
    __syncthreads();

    #pragma unroll
    for (int ks = 0; ks < 2; ++ks) {
      bf16x8 af[4], bfr[4];
      #pragma unroll
      for (int i = 0; i < 4; ++i)
        af[i] = *(const bf16x8*)&As[(wm * 64 + i * 16 + col) * SA + ks * 32 + quad * 8];
      #pragma unroll
      for (int j = 0; j < 4; ++j) {
        int n = wn * 64 + j * 16 + col;
        int p = (ks * 4 + quad) ^ (n & 7);
        bfr[j] = *(const bf16x8*)&Bs[n * BK + p * 8];
      }
      #pragma unroll
      for (int i = 0; i < 4; ++i) {
        #pragma unroll
        for (int j = 0; j < 4; ++j)
          acc[i][j] = __builtin_amdgcn_mfma_f32_16x16x32_bf16(af[i], bfr[j], acc[i][j], 0, 0, 0);
      }
    }
    __syncthreads();
  }

  // epilogue: C/D layout col=lane&15, row=quad*4+reg
  #pragma unroll
  for (int i = 0; i < 4; ++i) {
    #pragma unroll
    for (int r = 0; r < 4; ++r) {
      int m = m0 + wm * 64 + i * 16 + quad * 4 + r;
      float* orow = out + (size_t)m * N_DIM + n0 + wn * 64 + col;
      #pragma unroll
      for (int j = 0; j < 4; ++j)
        orow[j * 16] = acc[i][j][r] + bn[j];
    }
  }
}

extern "C" void kernel_launch(void* const* d_in, const int* in_sizes, int n_in,
                              void* d_out, int out_size, void* d_ws, size_t ws_size,
                              hipStream_t stream) {
  const float* x      = (const float*)d_in[0];
  const float* weight = (const float*)d_in[1];
  const float* bias   = (const float*)d_in[2];
  const float* downs  = (const float*)d_in[3];
  const float* ups    = (const float*)d_in[4];
  const float* scales = (const float*)d_in[5];
  float* out = (float*)d_out;
  bf16_t* weff = (bf16_t*)d_ws;  // N_DIM*K_DIM bf16 = 8.4 MB scratch

  dim3 g1(K_DIM / 64, N_DIM / 64);
  build_weff_kernel<<<g1, 256, 0, stream>>>(weight, downs, ups, scales, weff);

  dim3 g2(N_DIM / BN, M_DIM / BM);
  lora_gemm_kernel<<<g2, 256, 0, stream>>>(x, weff, bias, out);
}

// Round 2
// 405.791 us; speedup vs baseline: 1.1287x; 1.1287x over previous
//
#include <hip/hip_runtime.h>

// Problem constants (B=2, S=8192, IN=2048, OUT=2048, L=4, R=32)
#define M_DIM 16384
#define N_DIM 2048
#define K_DIM 2048
#define L_AD 4
#define R_AD 32

typedef __bf16 bf16_t;
typedef bf16_t bf16x8 __attribute__((ext_vector_type(8)));
typedef bf16_t bf16x4 __attribute__((ext_vector_type(4)));
typedef float f32x4 __attribute__((ext_vector_type(4)));

#define BM 128
#define BN 128
#define BK 64

__device__ __forceinline__ void async_load16(const void* g, void* l) {
  __builtin_amdgcn_global_load_lds(
      (const __attribute__((address_space(1))) unsigned int*)g,
      (__attribute__((address_space(3))) unsigned int*)l, 16, 0, 0);
}

// ---------------------------------------------------------------------------
// Kernel 0: x fp32 -> bf16 (33.5M elems). Pure bandwidth pass.
// ---------------------------------------------------------------------------
__global__ __launch_bounds__(256) void convert_x_kernel(
    const float* __restrict__ X, bf16_t* __restrict__ Xb) {
  const size_t base = ((size_t)blockIdx.x * 256 + threadIdx.x) * 8;
  f32x4 lo = *(const f32x4*)(X + base);
  f32x4 hi = *(const f32x4*)(X + base + 4);
  bf16x8 v;
  v[0] = (bf16_t)lo[0]; v[1] = (bf16_t)lo[1];
  v[2] = (bf16_t)lo[2]; v[3] = (bf16_t)lo[3];
  v[4] = (bf16_t)hi[0]; v[5] = (bf16_t)hi[1];
  v[6] = (bf16_t)hi[2]; v[7] = (bf16_t)hi[3];
  *(bf16x8*)(Xb + base) = v;
}

// ---------------------------------------------------------------------------
// Kernel 1: Weff[n,k] = bf16( W[n,k] + sum_l scale_l * sum_r ups[l,n,r]*downs[l,r,k] )
// ---------------------------------------------------------------------------
__global__ __launch_bounds__(256) void build_weff_kernel(
    const float* __restrict__ W, const float* __restrict__ downs,
    const float* __restrict__ ups, const float* __restrict__ scales,
    bf16_t* __restrict__ weff) {
  __shared__ float up_s[64 * 129];
  __shared__ float down_s[128 * 64];
  const int t = threadIdx.x;
  const int n0 = blockIdx.y * 64;
  const int k0 = blockIdx.x * 64;

  for (int l = 0; l < L_AD; ++l) {
    const float sc = scales[l];
    const float* up_l = ups + (size_t)l * N_DIM * R_AD;
    #pragma unroll
    for (int j = 0; j < 8; ++j) {
      int flat = j * 256 + t;
      int nl = flat >> 5, r = flat & 31;
      up_s[nl * 129 + l * 32 + r] = sc * up_l[(size_t)(n0 + nl) * R_AD + r];
    }
  }
  #pragma unroll
  for (int j = 0; j < 32; ++j) {
    int flat = j * 256 + t;
    int lr = flat >> 6, kk = flat & 63;
    down_s[lr * 64 + kk] = downs[(size_t)lr * K_DIM + k0 + kk];
  }
  __syncthreads();

  const int tn = t >> 4, tk = t & 15;
  float acc[4][4] = {};
  for (int lr = 0; lr < L_AD * R_AD; ++lr) {
    f32x4 b = *(const f32x4*)&down_s[lr * 64 + tk * 4];
    #pragma unroll
    for (int u = 0; u < 4; ++u) {
      float a = up_s[(tn * 4 + u) * 129 + lr];
      #pragma unroll
      for (int v = 0; v < 4; ++v) acc[u][v] += a * b[v];
    }
  }
  #pragma unroll
  for (int u = 0; u < 4; ++u) {
    int n = n0 + tn * 4 + u;
    f32x4 wv = *(const f32x4*)&W[(size_t)n * K_DIM + k0 + tk * 4];
    bf16x4 o;
    #pragma unroll
    for (int v = 0; v < 4; ++v) o[v] = (bf16_t)(acc[u][v] + wv[v]);
    *(bf16x4*)&weff[(size_t)n * K_DIM + k0 + tk * 4] = o;
  }
}

// ---------------------------------------------------------------------------
// Kernel 2 (fast path): out = Xb @ Weff^T + bias, both operands bf16 row-major.
// Pure m97 structure: 128x128 tile, BK=64, both operands via global_load_lds
// 16B with XOR-chunk swizzle; 4 waves, 4x4 grid of 16x16x32 bf16 MFMA.
// ---------------------------------------------------------------------------
__global__ __launch_bounds__(256) void gemm_bf16_kernel(
    const bf16_t* __restrict__ Xb, const bf16_t* __restrict__ Wb,
    const float* __restrict__ bias, float* __restrict__ out) {
  __shared__ __align__(16) bf16_t As[BM * BK];
  __shared__ __align__(16) bf16_t Bs[BN * BK];

  const int t = threadIdx.x;
  const int lane = t & 63;
  const int wv = t >> 6;
  const int wm = wv >> 1, wn = wv & 1;
  const int col = lane & 15, quad = lane >> 4;
  const int m0 = blockIdx.y * BM;
  const int n0 = blockIdx.x * BN;

  // staging: flat slot s = j*256 + t; row = s>>3 (0..127), oct = s&7.
  // slot (row, oct) holds global chunk c = oct ^ (row&7)  (8 bf16 per chunk)
  const int srow = t >> 3;
  const int soct = t & 7;

  f32x4 acc[4][4] = {};

  float bn[4];
  #pragma unroll
  for (int j = 0; j < 4; ++j) bn[j] = bias[n0 + wn * 64 + j * 16 + col];

  for (int kt = 0; kt < K_DIM / BK; ++kt) {
    const int kg = kt * BK;
    #pragma unroll
    for (int j = 0; j < 4; ++j) {
      int row = j * 32 + srow;
      int c = soct ^ (row & 7);
      async_load16(Wb + (size_t)(n0 + row) * K_DIM + kg + c * 8,
                   &Bs[(size_t)(row * 8 + soct) * 8]);
      async_load16(Xb + (size_t)(m0 + row) * K_DIM + kg + c * 8,
                   &As[(size_t)(row * 8 + soct) * 8]);
    }
    __syncthreads();

    #pragma unroll
    for (int ks = 0; ks < 2; ++ks) {
      bf16x8 af[4], bfr[4];
      #pragma unroll
      for (int i = 0; i < 4; ++i) {
        int row = wm * 64 + i * 16 + col;
        int p = (ks * 4 + quad) ^ (row & 7);
        af[i] = *(const bf16x8*)&As[row * BK + p * 8];
      }
      #pragma unroll
      for (int j = 0; j < 4; ++j) {
        int row = wn * 64 + j * 16 + col;
        int p = (ks * 4 + quad) ^ (row & 7);
        bfr[j] = *(const bf16x8*)&Bs[row * BK + p * 8];
      }
      #pragma unroll
      for (int i = 0; i < 4; ++i) {
        #pragma unroll
        for (int j = 0; j < 4; ++j)
          acc[i][j] = __builtin_amdgcn_mfma_f32_16x16x32_bf16(af[i], bfr[j], acc[i][j], 0, 0, 0);
      }
    }
    __syncthreads();
  }

  // epilogue: C/D layout col=lane&15, row=quad*4+reg
  #pragma unroll
  for (int i = 0; i < 4; ++i) {
    #pragma unroll
    for (int r = 0; r < 4; ++r) {
      int m = m0 + wm * 64 + i * 16 + quad * 4 + r;
      float* orow = out + (size_t)m * N_DIM + n0 + wn * 64 + col;
      #pragma unroll
      for (int j = 0; j < 4; ++j)
        orow[j * 16] = acc[i][j][r] + bn[j];
    }
  }
}

// ---------------------------------------------------------------------------
// Fallback GEMM (R1 version): fp32 A converted in-kernel. Used if ws too small.
// ---------------------------------------------------------------------------
#define SA 72
__global__ __launch_bounds__(256) void lora_gemm_fallback(
    const float* __restrict__ X, const bf16_t* __restrict__ Wb,
    const float* __restrict__ bias, float* __restrict__ out) {
  __shared__ __align__(16) bf16_t As[BM * SA];
  __shared__ __align__(16) bf16_t Bs[BN * BK];

  const int t = threadIdx.x;
  const int lane = t & 63;
  const int wv = t >> 6;
  const int wm = wv >> 1, wn = wv & 1;
  const int col = lane & 15, quad = lane >> 4;
  const int m0 = blockIdx.y * BM;
  const int n0 = blockIdx.x * BN;
  const int srow = t >> 3;
  const int soct = t & 7;

  f32x4 acc[4][4] = {};
  float bn[4];
  #pragma unroll
  for (int j = 0; j < 4; ++j) bn[j] = bias[n0 + wn * 64 + j * 16 + col];

  for (int kt = 0; kt < K_DIM / BK; ++kt) {
    const int kg = kt * BK;
    #pragma unroll
    for (int j = 0; j < 4; ++j) {
      int n = j * 32 + srow;
      int c = soct ^ (n & 7);
      async_load16(Wb + (size_t)(n0 + n) * K_DIM + kg + c * 8,
                   &Bs[(size_t)(j * 256 + t) * 8]);
    }
    #pragma unroll
    for (int j = 0; j < 4; ++j) {
      int m = j * 32 + srow;
      const f32x4* src = (const f32x4*)(X + (size_t)(m0 + m) * K_DIM + kg + soct * 8);
      f32x4 lo = src[0], hi = src[1];
      bf16x8 v;
      v[0] = (bf16_t)lo[0]; v[1] = (bf16_t)lo[1];
      v[2] = (bf16_t)lo[2]; v[3] = (bf16_t)lo[3];
      v[4] = (bf16_t)hi[0]; v[5] = (bf16_t)hi[1];
      v[6] = (bf16_t)hi[2]; v[7] = (bf16_t)hi[3];
      *(bf16x8*)&As[m * SA + soct * 8] = v;
    }
    __syncthreads();

    #pragma unroll
    for (int ks = 0; ks < 2; ++ks) {
      bf16x8 af[4], bfr[4];
      #pragma unroll
      for (int i = 0; i < 4; ++i)
        af[i] = *(const bf16x8*)&As[(wm * 64 + i * 16 + col) * SA + ks * 32 + quad * 8];
      #pragma unroll
      for (int j = 0; j < 4; ++j) {
        int n = wn * 64 + j * 16 + col;
        int p = (ks * 4 + quad) ^ (n & 7);
        bfr[j] = *(const bf16x8*)&Bs[n * BK + p * 8];
      }
      #pragma unroll
      for (int i = 0; i < 4; ++i) {
        #pragma unroll
        for (int j = 0; j < 4; ++j)
          acc[i][j] = __builtin_amdgcn_mfma_f32_16x16x32_bf16(af[i], bfr[j], acc[i][j], 0, 0, 0);
      }
    }
    __syncthreads();
  }

  #pragma unroll
  for (int i = 0; i < 4; ++i) {
    #pragma unroll
    for (int r = 0; r < 4; ++r) {
      int m = m0 + wm * 64 + i * 16 + quad * 4 + r;
      float* orow = out + (size_t)m * N_DIM + n0 + wn * 64 + col;
      #pragma unroll
      for (int j = 0; j < 4; ++j)
        orow[j * 16] = acc[i][j][r] + bn[j];
    }
  }
}

extern "C" void kernel_launch(void* const* d_in, const int* in_sizes, int n_in,
                              void* d_out, int out_size, void* d_ws, size_t ws_size,
                              hipStream_t stream) {
  const float* x      = (const float*)d_in[0];
  const float* weight = (const float*)d_in[1];
  const float* bias   = (const float*)d_in[2];
  const float* downs  = (const float*)d_in[3];
  const float* ups    = (const float*)d_in[4];
  const float* scales = (const float*)d_in[5];
  float* out = (float*)d_out;

  const size_t weff_bytes = (size_t)N_DIM * K_DIM * 2;            // 8.4 MB
  const size_t xb_bytes   = (size_t)M_DIM * K_DIM * 2;            // 67 MB
  bf16_t* weff = (bf16_t*)d_ws;

  dim3 g1(K_DIM / 64, N_DIM / 64);
  build_weff_kernel<<<g1, 256, 0, stream>>>(weight, downs, ups, scales, weff);

  dim3 g2(N_DIM / BN, M_DIM / BM);
  if (ws_size >= weff_bytes + xb_bytes) {
    bf16_t* xb = (bf16_t*)((char*)d_ws + weff_bytes);
    const size_t n_elem = (size_t)M_DIM * K_DIM;
    convert_x_kernel<<<(unsigned)(n_elem / (256 * 8)), 256, 0, stream>>>(x, xb);
    gemm_bf16_kernel<<<g2, 256, 0, stream>>>(xb, weff, bias, out);
  } else {
    lora_gemm_fallback<<<g2, 256, 0, stream>>>(x, weff, bias, out);
  }
}

// Round 3
// 398.558 us; speedup vs baseline: 1.1492x; 1.0181x over previous
//
#include <hip/hip_runtime.h>

// Problem constants (B=2, S=8192, IN=2048, OUT=2048, L=4, R=32)
#define M_DIM 16384
#define N_DIM 2048
#define K_DIM 2048
#define L_AD 4
#define R_AD 32

typedef __bf16 bf16_t;
typedef bf16_t bf16x8 __attribute__((ext_vector_type(8)));
typedef bf16_t bf16x4 __attribute__((ext_vector_type(4)));
typedef float f32x4 __attribute__((ext_vector_type(4)));
typedef float f32x16 __attribute__((ext_vector_type(16)));

#define BM 128
#define BN 128
#define BK 64

__device__ __forceinline__ void async_load16(const void* g, void* l) {
  __builtin_amdgcn_global_load_lds(
      (const __attribute__((address_space(1))) unsigned int*)g,
      (__attribute__((address_space(3))) unsigned int*)l, 16, 0, 0);
}

// ---------------------------------------------------------------------------
// Kernel 0: x fp32 -> bf16 (33.5M elems). Pure bandwidth pass.
// ---------------------------------------------------------------------------
__global__ __launch_bounds__(256) void convert_x_kernel(
    const float* __restrict__ X, bf16_t* __restrict__ Xb) {
  const size_t base = ((size_t)blockIdx.x * 256 + threadIdx.x) * 8;
  f32x4 lo = *(const f32x4*)(X + base);
  f32x4 hi = *(const f32x4*)(X + base + 4);
  bf16x8 v;
  v[0] = (bf16_t)lo[0]; v[1] = (bf16_t)lo[1];
  v[2] = (bf16_t)lo[2]; v[3] = (bf16_t)lo[3];
  v[4] = (bf16_t)hi[0]; v[5] = (bf16_t)hi[1];
  v[6] = (bf16_t)hi[2]; v[7] = (bf16_t)hi[3];
  *(bf16x8*)(Xb + base) = v;
}

// ---------------------------------------------------------------------------
// Kernel 1: Weff[n,k] = bf16( W[n,k] + sum_l scale_l * sum_r ups[l,n,r]*downs[l,r,k] )
// ---------------------------------------------------------------------------
__global__ __launch_bounds__(256) void build_weff_kernel(
    const float* __restrict__ W, const float* __restrict__ downs,
    const float* __restrict__ ups, const float* __restrict__ scales,
    bf16_t* __restrict__ weff) {
  __shared__ float up_s[64 * 129];
  __shared__ float down_s[128 * 64];
  const int t = threadIdx.x;
  const int n0 = blockIdx.y * 64;
  const int k0 = blockIdx.x * 64;

  for (int l = 0; l < L_AD; ++l) {
    const float sc = scales[l];
    const float* up_l = ups + (size_t)l * N_DIM * R_AD;
    #pragma unroll
    for (int j = 0; j < 8; ++j) {
      int flat = j * 256 + t;
      int nl = flat >> 5, r = flat & 31;
      up_s[nl * 129 + l * 32 + r] = sc * up_l[(size_t)(n0 + nl) * R_AD + r];
    }
  }
  #pragma unroll
  for (int j = 0; j < 32; ++j) {
    int flat = j * 256 + t;
    int lr = flat >> 6, kk = flat & 63;
    down_s[lr * 64 + kk] = downs[(size_t)lr * K_DIM + k0 + kk];
  }
  __syncthreads();

  const int tn = t >> 4, tk = t & 15;
  float acc[4][4] = {};
  for (int lr = 0; lr < L_AD * R_AD; ++lr) {
    f32x4 b = *(const f32x4*)&down_s[lr * 64 + tk * 4];
    #pragma unroll
    for (int u = 0; u < 4; ++u) {
      float a = up_s[(tn * 4 + u) * 129 + lr];
      #pragma unroll
      for (int v = 0; v < 4; ++v) acc[u][v] += a * b[v];
    }
  }
  #pragma unroll
  for (int u = 0; u < 4; ++u) {
    int n = n0 + tn * 4 + u;
    f32x4 wv = *(const f32x4*)&W[(size_t)n * K_DIM + k0 + tk * 4];
    bf16x4 o;
    #pragma unroll
    for (int v = 0; v < 4; ++v) o[v] = (bf16_t)(acc[u][v] + wv[v]);
    *(bf16x4*)&weff[(size_t)n * K_DIM + k0 + tk * 4] = o;
  }
}

// ---------------------------------------------------------------------------
// Kernel 2 (fast path): out = Xb @ Weff^T + bias, both operands bf16 row-major.
// m97 staging (global_load_lds 16B + XOR-chunk swizzle) with 32x32x16 MFMA:
// 4 waves (2x2), each a 2x2 grid of 32x32 tiles (m119: 32x32 pipe ~15% faster).
// A/B frag: [m|n]=lane&31, k=(lane>>5)*8+j. C/D: col=lane&31,
// row=(reg&3)+8*(reg>>2)+4*(lane>>5).
// ---------------------------------------------------------------------------
__global__ __launch_bounds__(256) void gemm_bf16_kernel(
    const bf16_t* __restrict__ Xb, const bf16_t* __restrict__ Wb,
    const float* __restrict__ bias, float* __restrict__ out) {
  __shared__ __align__(16) bf16_t As[BM * BK];
  __shared__ __align__(16) bf16_t Bs[BN * BK];

  const int t = threadIdx.x;
  const int lane = t & 63;
  const int wv = t >> 6;
  const int wm = wv >> 1, wn = wv & 1;
  const int l5 = lane & 31;     // row within a 32x32 tile
  const int half = lane >> 5;   // k-octet half selector
  const int m0 = blockIdx.y * BM;
  const int n0 = blockIdx.x * BN;

  // staging: flat slot s = j*256 + t; row = s>>3 (0..127), oct = s&7.
  // slot (row, oct) holds global chunk c = oct ^ (row&7)  (8 bf16 per chunk)
  const int srow = t >> 3;
  const int soct = t & 7;

  f32x16 acc[2][2] = {};

  float bn[2];
  #pragma unroll
  for (int j = 0; j < 2; ++j) bn[j] = bias[n0 + wn * 64 + j * 32 + l5];

  for (int kt = 0; kt < K_DIM / BK; ++kt) {
    const int kg = kt * BK;
    #pragma unroll
    for (int j = 0; j < 4; ++j) {
      int row = j * 32 + srow;
      int c = soct ^ (row & 7);
      async_load16(Wb + (size_t)(n0 + row) * K_DIM + kg + c * 8,
                   &Bs[(size_t)(row * 8 + soct) * 8]);
      async_load16(Xb + (size_t)(m0 + row) * K_DIM + kg + c * 8,
                   &As[(size_t)(row * 8 + soct) * 8]);
    }
    __syncthreads();

    #pragma unroll
    for (int ks = 0; ks < 4; ++ks) {
      bf16x8 af[2], bfr[2];
      #pragma unroll
      for (int i = 0; i < 2; ++i) {
        int row = wm * 64 + i * 32 + l5;
        int p = (ks * 2 + half) ^ (row & 7);
        af[i] = *(const bf16x8*)&As[row * BK + p * 8];
      }
      #pragma unroll
      for (int j = 0; j < 2; ++j) {
        int row = wn * 64 + j * 32 + l5;
        int p = (ks * 2 + half) ^ (row & 7);
        bfr[j] = *(const bf16x8*)&Bs[row * BK + p * 8];
      }
      #pragma unroll
      for (int i = 0; i < 2; ++i) {
        #pragma unroll
        for (int j = 0; j < 2; ++j)
          acc[i][j] = __builtin_amdgcn_mfma_f32_32x32x16_bf16(af[i], bfr[j], acc[i][j], 0, 0, 0);
      }
    }
    __syncthreads();
  }

  // epilogue: C/D layout col=lane&31, row=(reg&3)+8*(reg>>2)+4*(lane>>5)
  #pragma unroll
  for (int i = 0; i < 2; ++i) {
    #pragma unroll
    for (int j = 0; j < 2; ++j) {
      int n = n0 + wn * 64 + j * 32 + l5;
      #pragma unroll
      for (int r = 0; r < 16; ++r) {
        int m = m0 + wm * 64 + i * 32 + (r & 3) + 8 * (r >> 2) + 4 * half;
        out[(size_t)m * N_DIM + n] = acc[i][j][r] + bn[j];
      }
    }
  }
}

// ---------------------------------------------------------------------------
// Fallback GEMM (R1 version): fp32 A converted in-kernel. Used if ws too small.
// ---------------------------------------------------------------------------
#define SA 72
__global__ __launch_bounds__(256) void lora_gemm_fallback(
    const float* __restrict__ X, const bf16_t* __restrict__ Wb,
    const float* __restrict__ bias, float* __restrict__ out) {
  __shared__ __align__(16) bf16_t As[BM * SA];
  __shared__ __align__(16) bf16_t Bs[BN * BK];

  const int t = threadIdx.x;
  const int lane = t & 63;
  const int wv = t >> 6;
  const int wm = wv >> 1, wn = wv & 1;
  const int col = lane & 15, quad = lane >> 4;
  const int m0 = blockIdx.y * BM;
  const int n0 = blockIdx.x * BN;
  const int srow = t >> 3;
  const int soct = t & 7;

  f32x4 acc[4][4] = {};
  float bn[4];
  #pragma unroll
  for (int j = 0; j < 4; ++j) bn[j] = bias[n0 + wn * 64 + j * 16 + col];

  for (int kt = 0; kt < K_DIM / BK; ++kt) {
    const int kg = kt * BK;
    #pragma unroll
    for (int j = 0; j < 4; ++j) {
      int n = j * 32 + srow;
      int c = soct ^ (n & 7);
      async_load16(Wb + (size_t)(n0 + n) * K_DIM + kg + c * 8,
                   &Bs[(size_t)(j * 256 + t) * 8]);
    }
    #pragma unroll
    for (int j = 0; j < 4; ++j) {
      int m = j * 32 + srow;
      const f32x4* src = (const f32x4*)(X + (size_t)(m0 + m) * K_DIM + kg + soct * 8);
      f32x4 lo = src[0], hi = src[1];
      bf16x8 v;
      v[0] = (bf16_t)lo[0]; v[1] = (bf16_t)lo[1];
      v[2] = (bf16_t)lo[2]; v[3] = (bf16_t)lo[3];
      v[4] = (bf16_t)hi[0]; v[5] = (bf16_t)hi[1];
      v[6] = (bf16_t)hi[2]; v[7] = (bf16_t)hi[3];
      *(bf16x8*)&As[m * SA + soct * 8] = v;
    }
    __syncthreads();

    #pragma unroll
    for (int ks = 0; ks < 2; ++ks) {
      bf16x8 af[4], bfr[4];
      #pragma unroll
      for (int i = 0; i < 4; ++i)
        af[i] = *(const bf16x8*)&As[(wm * 64 + i * 16 + col) * SA + ks * 32 + quad * 8];
      #pragma unroll
      for (int j = 0; j < 4; ++j) {
        int n = wn * 64 + j * 16 + col;
        int p = (ks * 4 + quad) ^ (n & 7);
        bfr[j] = *(const bf16x8*)&Bs[n * BK + p * 8];
      }
      #pragma unroll
      for (int i = 0; i < 4; ++i) {
        #pragma unroll
        for (int j = 0; j < 4; ++j)
          acc[i][j] = __builtin_amdgcn_mfma_f32_16x16x32_bf16(af[i], bfr[j], acc[i][j], 0, 0, 0);
      }
    }
    __syncthreads();
  }

  #pragma unroll
  for (int i = 0; i < 4; ++i) {
    #pragma unroll
    for (int r = 0; r < 4; ++r) {
      int m = m0 + wm * 64 + i * 16 + quad * 4 + r;
      float* orow = out + (size_t)m * N_DIM + n0 + wn * 64 + col;
      #pragma unroll
      for (int j = 0; j < 4; ++j)
        orow[j * 16] = acc[i][j][r] + bn[j];
    }
  }
}

extern "C" void kernel_launch(void* const* d_in, const int* in_sizes, int n_in,
                              void* d_out, int out_size, void* d_ws, size_t ws_size,
                              hipStream_t stream) {
  const float* x      = (const float*)d_in[0];
  const float* weight = (const float*)d_in[1];
  const float* bias   = (const float*)d_in[2];
  const float* downs  = (const float*)d_in[3];
  const float* ups    = (const float*)d_in[4];
  const float* scales = (const float*)d_in[5];
  float* out = (float*)d_out;

  const size_t weff_bytes = (size_t)N_DIM * K_DIM * 2;            // 8.4 MB
  const size_t xb_bytes   = (size_t)M_DIM * K_DIM * 2;            // 67 MB
  bf16_t* weff = (bf16_t*)d_ws;

  dim3 g1(K_DIM / 64, N_DIM / 64);
  build_weff_kernel<<<g1, 256, 0, stream>>>(weight, downs, ups, scales, weff);

  dim3 g2(N_DIM / BN, M_DIM / BM);
  if (ws_size >= weff_bytes + xb_bytes) {
    bf16_t* xb = (bf16_t*)((char*)d_ws + weff_bytes);
    const size_t n_elem = (size_t)M_DIM * K_DIM;
    convert_x_kernel<<<(unsigned)(n_elem / (256 * 8)), 256, 0, stream>>>(x, xb);
    gemm_bf16_kernel<<<g2, 256, 0, stream>>>(xb, weff, bias, out);
  } else {
    lora_gemm_fallback<<<g2, 256, 0, stream>>>(x, weff, bias, out);
  }
}